// Round 1
// baseline (370.949 us; speedup 1.0000x reference)
//
#include <hip/hip_runtime.h>

// FP8 MLP, fully fused:  out = q(relu(q(x)@q(w1)^T)) @ q(w2)^T
// x[32768,784] f32, w1[4096,784] f32, w2[10,4096] f32, out[32768,10] f32.
// Strategy: pre-quantize w1/w2 to e4m3 in ws; one fused kernel per 128 batch
// rows keeps the quantized x-panel resident in LDS, streams w1 tiles with
// global_load_lds (T3/T4 single-barrier pipeline), accumulates fc2 in regs.

typedef float f32x4 __attribute__((ext_vector_type(4)));

#define DIN 784
#define KP  832          // 13 * 64 (zero-padded K)
#define DH  4096
#define NKS 13
#define NCH 32

__device__ __forceinline__ void gload_lds16(const void* g, void* l) {
  __builtin_amdgcn_global_load_lds(
      (const __attribute__((address_space(1))) unsigned int*)g,
      (__attribute__((address_space(3))) unsigned int*)l, 16, 0, 0);
}

// ---------- weight quantization (fp32 -> OCP e4m3, RNE via HW cvt) ----------

__global__ __launch_bounds__(256) void quant_w1_k(const float* __restrict__ w1,
                                                  unsigned char* __restrict__ w1q) {
  int idx = blockIdx.x * 256 + threadIdx.x;       // 4096 rows * 52 chunks(16B)
  int r = idx / 52, c = idx % 52;
  uint4 v = make_uint4(0u, 0u, 0u, 0u);
  if (c < 49) {                                   // 49*16 = 784 valid cols
    const float4* p = (const float4*)(w1 + (size_t)r * DIN + c * 16);
    float4 f0 = p[0], f1 = p[1], f2 = p[2], f3 = p[3];
    int a = __builtin_amdgcn_cvt_pk_fp8_f32(f0.x, f0.y, 0, false);
    a     = __builtin_amdgcn_cvt_pk_fp8_f32(f0.z, f0.w, a, true);
    int b = __builtin_amdgcn_cvt_pk_fp8_f32(f1.x, f1.y, 0, false);
    b     = __builtin_amdgcn_cvt_pk_fp8_f32(f1.z, f1.w, b, true);
    int cc = __builtin_amdgcn_cvt_pk_fp8_f32(f2.x, f2.y, 0, false);
    cc    = __builtin_amdgcn_cvt_pk_fp8_f32(f2.z, f2.w, cc, true);
    int d = __builtin_amdgcn_cvt_pk_fp8_f32(f3.x, f3.y, 0, false);
    d     = __builtin_amdgcn_cvt_pk_fp8_f32(f3.z, f3.w, d, true);
    v = make_uint4((unsigned)a, (unsigned)b, (unsigned)cc, (unsigned)d);
  }
  *(uint4*)(w1q + (size_t)r * KP + c * 16) = v;   // pad cols 784..831 = 0
}

__global__ __launch_bounds__(256) void quant_w2_k(const float* __restrict__ w2,
                                                  unsigned char* __restrict__ w2q) {
  int idx = blockIdx.x * 256 + threadIdx.x;       // 16 rows * 256 chunks(16B)
  int r = idx >> 8, c = idx & 255;
  uint4 v = make_uint4(0u, 0u, 0u, 0u);
  if (r < 10) {
    const float4* p = (const float4*)(w2 + (size_t)r * DH + c * 16);
    float4 f0 = p[0], f1 = p[1], f2 = p[2], f3 = p[3];
    int a = __builtin_amdgcn_cvt_pk_fp8_f32(f0.x, f0.y, 0, false);
    a     = __builtin_amdgcn_cvt_pk_fp8_f32(f0.z, f0.w, a, true);
    int b = __builtin_amdgcn_cvt_pk_fp8_f32(f1.x, f1.y, 0, false);
    b     = __builtin_amdgcn_cvt_pk_fp8_f32(f1.z, f1.w, b, true);
    int cc = __builtin_amdgcn_cvt_pk_fp8_f32(f2.x, f2.y, 0, false);
    cc    = __builtin_amdgcn_cvt_pk_fp8_f32(f2.z, f2.w, cc, true);
    int d = __builtin_amdgcn_cvt_pk_fp8_f32(f3.x, f3.y, 0, false);
    d     = __builtin_amdgcn_cvt_pk_fp8_f32(f3.z, f3.w, d, true);
    v = make_uint4((unsigned)a, (unsigned)b, (unsigned)cc, (unsigned)d);
  }
  *(uint4*)(w2q + (size_t)r * DH + c * 16) = v;   // rows 10..15 = 0
}

// ------------------------------ fused MLP -----------------------------------
// Block = 256 threads (4 waves), owns 128 batch rows. Grid = 256 blocks.
// LDS: A-panel 104KB (persistent, k-subtiled [k/8][128][8]),
//      B double-buffer 16KB (row-major [128][64], 16B XOR-swizzled),
//      H chunk 16KB (k-subtiled, fc2 A-operand layout).  Total 136KB.

__global__ __launch_bounds__(256, 1)
void fused_mlp(const float* __restrict__ x,
               const unsigned char* __restrict__ w1q,
               const unsigned char* __restrict__ w2q,
               float* __restrict__ out) {
  __shared__ unsigned long long A[KP / 8][128];   // A[kg][r] = 8 fp8, k=kg*8+j
  __shared__ unsigned char Bt[2][8192];           // [128 n][64 k] swizzled
  __shared__ unsigned long long H[16][128];       // H[kg][r], chunk-local k

  const int tid = threadIdx.x;
  const int lane = tid & 63;
  const int w  = tid >> 6;          // wave 0..3
  const int lr = lane & 15;
  const int lg = lane >> 4;
  const int wm = w >> 1, wn = w & 1; // wave -> 64x64 quadrant of 128x128
  const long row0 = (long)blockIdx.x * 128;

  // ---- prologue: quantize this block's x rows into LDS A-panel ----
  for (int idx = tid; idx < 128 * (KP / 8); idx += 256) {
    int r = idx / (KP / 8), kg = idx - r * (KP / 8);
    unsigned long long v = 0ull;
    if (kg < DIN / 8) {                                  // 98 valid 8-groups
      const float4* p = (const float4*)(x + (row0 + r) * DIN + kg * 8);
      float4 f0 = p[0], f1 = p[1];
      int lo = __builtin_amdgcn_cvt_pk_fp8_f32(f0.x, f0.y, 0, false);
      lo     = __builtin_amdgcn_cvt_pk_fp8_f32(f0.z, f0.w, lo, true);
      int hi = __builtin_amdgcn_cvt_pk_fp8_f32(f1.x, f1.y, 0, false);
      hi     = __builtin_amdgcn_cvt_pk_fp8_f32(f1.z, f1.w, hi, true);
      v = (unsigned long long)(unsigned)lo |
          ((unsigned long long)(unsigned)hi << 32);
    }
    A[kg][r] = v;
  }

  f32x4 acc2[2] = {};   // fc2 accumulator: rows w*32 + mi2*16, cols 0..15

  // stage B(nch=0, ks=0) into Bt[0]; source pre-swizzled (rule #21)
#define STAGE_B(nch_, ks_, b_)                                                 \
  do {                                                                         \
    _Pragma("unroll") for (int i_ = 0; i_ < 2; ++i_) {                         \
      int cc_ = tid + i_ * 256;                                                \
      int n_ = cc_ >> 2, c16_ = cc_ & 3;                                       \
      const unsigned char* src_ = w1q + (size_t)((nch_)*128 + n_) * KP +       \
                                  (ks_)*64 + ((c16_ ^ (n_ & 3)) << 4);         \
      gload_lds16(src_, &Bt[b_][cc_ * 16]);                                    \
    }                                                                          \
  } while (0)

  STAGE_B(0, 0, 0);
  __syncthreads();   // A-panel ready; first B tile drained

  int buf = 0;
  for (int nch = 0; nch < NCH; ++nch) {
    f32x4 acc1[4][4] = {};
    for (int ks = 0; ks < NKS; ++ks) {
      // issue next tile's loads (stays in flight across compute)
      if (ks < NKS - 1)       STAGE_B(nch, ks + 1, buf ^ 1);
      else if (nch < NCH - 1) STAGE_B(nch + 1, 0, buf ^ 1);

      // ---- fc1: 32 MFMAs on current tile ----
#pragma unroll
      for (int kk = 0; kk < 2; ++kk) {
        long a[4], b[4];
#pragma unroll
        for (int mi = 0; mi < 4; ++mi)
          a[mi] = (long)A[ks * 8 + kk * 4 + lg][wm * 64 + mi * 16 + lr];
#pragma unroll
        for (int ni = 0; ni < 4; ++ni) {
          int n = wn * 64 + ni * 16 + lr;
          int cb = kk * 32 + lg * 8;
          b[ni] = *(const long long*)&Bt[buf][n * 64 + (cb ^ ((n & 3) << 4))];
        }
#pragma unroll
        for (int mi = 0; mi < 4; ++mi)
#pragma unroll
          for (int ni = 0; ni < 4; ++ni)
            acc1[mi][ni] = __builtin_amdgcn_mfma_f32_16x16x32_fp8_fp8(
                a[mi], b[ni], acc1[mi][ni], 0, 0, 0);
      }

      if (ks == NKS - 1) {
        // ---- chunk epilogue: relu + quantize -> H (fc2 A layout) ----
        unsigned char* H8 = (unsigned char*)&H[0][0];
#pragma unroll
        for (int mi = 0; mi < 4; ++mi) {
#pragma unroll
          for (int ni = 0; ni < 4; ++ni) {
            f32x4 v = acc1[mi][ni];
            int k2 = wn * 64 + ni * 16 + lr;                  // chunk-local dh
            int base = (k2 >> 3) * 1024 + (wm * 64 + mi * 16 + 4 * lg) * 8 +
                       (k2 & 7);
            int p01 = __builtin_amdgcn_cvt_pk_fp8_f32(fmaxf(v[0], 0.f),
                                                      fmaxf(v[1], 0.f), 0, false);
            int p23 = __builtin_amdgcn_cvt_pk_fp8_f32(fmaxf(v[2], 0.f),
                                                      fmaxf(v[3], 0.f), 0, false);
            H8[base]      = (unsigned char)(p01 & 0xff);
            H8[base + 8]  = (unsigned char)((p01 >> 8) & 0xff);
            H8[base + 16] = (unsigned char)(p23 & 0xff);
            H8[base + 24] = (unsigned char)((p23 >> 8) & 0xff);
          }
        }
        asm volatile("s_waitcnt lgkmcnt(0)" ::: "memory");
        __builtin_amdgcn_s_barrier();
        asm volatile("" ::: "memory");
        // ---- fc2: 8 MFMAs, out += q(h_chunk) @ q(w2_chunk)^T ----
#pragma unroll
        for (int kk = 0; kk < 4; ++kk) {
          long b2 = *(const long long*)(w2q + (size_t)lr * DH + nch * 128 +
                                        kk * 32 + lg * 8);
#pragma unroll
          for (int mi2 = 0; mi2 < 2; ++mi2) {
            long a2 = (long)H[kk * 4 + lg][w * 32 + mi2 * 16 + lr];
            acc2[mi2] = __builtin_amdgcn_mfma_f32_16x16x32_fp8_fp8(
                a2, b2, acc2[mi2], 0, 0, 0);
          }
        }
      }

      // next tile landed; one barrier per K-step (T3 recipe)
      asm volatile("s_waitcnt vmcnt(0)" ::: "memory");
      __builtin_amdgcn_s_barrier();
      asm volatile("" ::: "memory");
      buf ^= 1;
    }
  }

  // ---- store out[128][10] f32 ----
  if (lr < 10) {
#pragma unroll
    for (int mi2 = 0; mi2 < 2; ++mi2)
#pragma unroll
      for (int j = 0; j < 4; ++j) {
        long rg = row0 + w * 32 + mi2 * 16 + 4 * lg + j;
        out[rg * 10 + lr] = acc2[mi2][j];
      }
  }
#undef STAGE_B
}

extern "C" void kernel_launch(void* const* d_in, const int* in_sizes, int n_in,
                              void* d_out, int out_size, void* d_ws, size_t ws_size,
                              hipStream_t stream) {
  const float* x  = (const float*)d_in[0];
  const float* w1 = (const float*)d_in[1];
  const float* w2 = (const float*)d_in[2];
  float* out = (float*)d_out;

  unsigned char* w1q = (unsigned char*)d_ws;            // [4096][832] fp8
  unsigned char* w2q = w1q + (size_t)DH * KP;           // [16][4096] fp8

  quant_w1_k<<<(DH * (KP / 16)) / 256, 256, 0, stream>>>(w1, w1q);
  quant_w2_k<<<16, 256, 0, stream>>>(w2, w2q);
  fused_mlp<<<32768 / 128, 256, 0, stream>>>(x, w1q, w2q, out);
}

// Round 2
// 232.291 us; speedup vs baseline: 1.5969x; 1.5969x over previous
//
#include <hip/hip_runtime.h>

// FP8 MLP, fully fused:  out = q(relu(q(x)@q(w1)^T)) @ q(w2)^T
// x[32768,784] f32, w1[4096,784] f32, w2[10,4096] f32, out[32768,10] f32.
// R2: 8-wave blocks, M=64 rows, grid=512 -> 2 blocks/CU (4 waves/SIMD).
// w1q stored k-interleaved so one ds_read_b128 = both kk fragments.

typedef float f32x4 __attribute__((ext_vector_type(4)));

#define DIN 784
#define KP  832          // 13 * 64 (zero-padded K)
#define DH  4096
#define NKS 13
#define NCH 32

__device__ __forceinline__ void gload_lds16(const void* g, void* l) {
  __builtin_amdgcn_global_load_lds(
      (const __attribute__((address_space(1))) unsigned int*)g,
      (__attribute__((address_space(3))) unsigned int*)l, 16, 0, 0);
}

__device__ __forceinline__ unsigned long long q8(float4 a, float4 b) {
  int lo = __builtin_amdgcn_cvt_pk_fp8_f32(a.x, a.y, 0, false);
  lo     = __builtin_amdgcn_cvt_pk_fp8_f32(a.z, a.w, lo, true);
  int hi = __builtin_amdgcn_cvt_pk_fp8_f32(b.x, b.y, 0, false);
  hi     = __builtin_amdgcn_cvt_pk_fp8_f32(b.z, b.w, hi, true);
  return (unsigned long long)(unsigned)lo |
         ((unsigned long long)(unsigned)hi << 32);
}

// ---------- weight quantization (fp32 -> OCP e4m3, RNE via HW cvt) ----------
// w1q layout: row n = 13 k-blocks of 64B; block ks = 4 groups lg of 16B;
// group = { q(w1[n][ks*64+lg*8 .. +8]) , q(w1[n][ks*64+32+lg*8 .. +8]) }.
// One 16B group == the two kk-fragments one lane needs for a 64-k tile.

__global__ __launch_bounds__(256) void quant_w1_k(const float* __restrict__ w1,
                                                  unsigned char* __restrict__ w1q) {
  int idx = blockIdx.x * 256 + threadIdx.x;       // 4096 n * 52 groups
  int n = idx / 52, g = idx % 52;
  int ks = g >> 2, lg = g & 3;
  int kA = ks * 64 + lg * 8, kB = kA + 32;
  const float* r = w1 + (size_t)n * DIN;
  unsigned long long va = 0ull, vb = 0ull;
  if (kA < DIN) va = q8(*(const float4*)(r + kA), *(const float4*)(r + kA + 4));
  if (kB < DIN) vb = q8(*(const float4*)(r + kB), *(const float4*)(r + kB + 4));
  ulonglong2 v; v.x = va; v.y = vb;
  *(ulonglong2*)(w1q + (size_t)n * KP + ks * 64 + lg * 16) = v;
}

__global__ __launch_bounds__(256) void quant_w2_k(const float* __restrict__ w2,
                                                  unsigned char* __restrict__ w2q) {
  int idx = blockIdx.x * 256 + threadIdx.x;       // 16 rows * 256 chunks(16B)
  int r = idx >> 8, c = idx & 255;
  ulonglong2 v; v.x = 0ull; v.y = 0ull;
  if (r < 10) {
    const float* p = w2 + (size_t)r * DH + c * 16;
    v.x = q8(*(const float4*)(p), *(const float4*)(p + 4));
    v.y = q8(*(const float4*)(p + 8), *(const float4*)(p + 12));
  }
  *(ulonglong2*)(w2q + (size_t)r * DH + c * 16) = v;  // rows 10..15 = 0
}

// ------------------------------ fused MLP -----------------------------------
// Block = 512 threads (8 waves), owns 64 batch rows. Grid = 512 -> 2 blk/CU.
// LDS: A panel 52KB persistent ([ks13][r64][lg4][16B], k-interleaved),
//      B dbuf 2x8KB ([n128][lg4][16B]), H 8KB (row-major [64][128], XOR swz).
// fc1: waves 2x4 over 64x128 chunk, each 32x32 (acc 2x2 frags, 8 MFMA/K-step).
// fc2: wave w -> rows (w&3)*16, dh-half (w>>2)*64; pair-reduced at the end.

__global__ __launch_bounds__(512, 4)
void fused_mlp(const float* __restrict__ x,
               const unsigned char* __restrict__ w1q,
               const unsigned char* __restrict__ w2q,
               float* __restrict__ out) {
  __shared__ unsigned char A[NKS * 4096];   // 52 KB
  __shared__ unsigned char Bt[2][8192];     // 16 KB
  __shared__ unsigned char H[64 * 128];     // 8 KB

  const int tid = threadIdx.x;
  const int lane = tid & 63;
  const int w  = tid >> 6;
  const int lr = lane & 15;
  const int lg = lane >> 4;
  const int wm = w >> 2, wn = w & 3;        // fc1: rows wm*32+, cols wn*32+
  const int wh = w & 3,  wk = w >> 2;       // fc2: rows wh*16+, dh-half wk*64+
  const long row0 = (long)blockIdx.x * 64;

#define STAGE(nch_, ks_, b_)                                                   \
  do {                                                                         \
    int n_ = tid >> 2, lg_ = tid & 3;                                          \
    gload_lds16(w1q + (size_t)((nch_)*128 + n_) * KP + (ks_)*64 + lg_*16,      \
                &Bt[b_][tid * 16]);                                            \
  } while (0)

  STAGE(0, 0, 0);   // in flight under the prologue

  // ---- prologue: quantize this block's 64 x-rows into the A panel ----
  for (int idx = tid; idx < NKS * 256; idx += 512) {
    int ks = idx >> 8, r = (idx >> 2) & 63, lgq = idx & 3;
    int kA = ks * 64 + lgq * 8, kB = kA + 32;
    const float* xr = x + (row0 + r) * DIN;
    unsigned long long va = 0ull, vb = 0ull;
    if (kA < DIN) va = q8(*(const float4*)(xr + kA), *(const float4*)(xr + kA + 4));
    if (kB < DIN) vb = q8(*(const float4*)(xr + kB), *(const float4*)(xr + kB + 4));
    ulonglong2 v; v.x = va; v.y = vb;
    *(ulonglong2*)&A[idx * 16] = v;
  }
  __syncthreads();   // A panel ready; first B tile drained

  f32x4 acc2 = {};
  int buf = 0;
  for (int nch = 0; nch < NCH; ++nch) {
    f32x4 acc1[2][2] = {{{}, {}}, {{}, {}}};
#pragma unroll
    for (int ks = 0; ks < NKS; ++ks) {
      if (ks < NKS - 1)       STAGE(nch, ks + 1, buf ^ 1);
      else if (nch < NCH - 1) STAGE(nch + 1, 0, buf ^ 1);

      // ---- fc1: 4 b128 frag reads, 8 MFMAs ----
      ulonglong2 a0 = *(const ulonglong2*)&A[ks*4096 + (wm*32      + lr)*64 + lg*16];
      ulonglong2 a1 = *(const ulonglong2*)&A[ks*4096 + (wm*32 + 16 + lr)*64 + lg*16];
      ulonglong2 b0 = *(const ulonglong2*)&Bt[buf][(wn*32      + lr)*64 + lg*16];
      ulonglong2 b1 = *(const ulonglong2*)&Bt[buf][(wn*32 + 16 + lr)*64 + lg*16];
      acc1[0][0] = __builtin_amdgcn_mfma_f32_16x16x32_fp8_fp8((long)a0.x, (long)b0.x, acc1[0][0], 0, 0, 0);
      acc1[0][1] = __builtin_amdgcn_mfma_f32_16x16x32_fp8_fp8((long)a0.x, (long)b1.x, acc1[0][1], 0, 0, 0);
      acc1[1][0] = __builtin_amdgcn_mfma_f32_16x16x32_fp8_fp8((long)a1.x, (long)b0.x, acc1[1][0], 0, 0, 0);
      acc1[1][1] = __builtin_amdgcn_mfma_f32_16x16x32_fp8_fp8((long)a1.x, (long)b1.x, acc1[1][1], 0, 0, 0);
      acc1[0][0] = __builtin_amdgcn_mfma_f32_16x16x32_fp8_fp8((long)a0.y, (long)b0.y, acc1[0][0], 0, 0, 0);
      acc1[0][1] = __builtin_amdgcn_mfma_f32_16x16x32_fp8_fp8((long)a0.y, (long)b1.y, acc1[0][1], 0, 0, 0);
      acc1[1][0] = __builtin_amdgcn_mfma_f32_16x16x32_fp8_fp8((long)a1.y, (long)b0.y, acc1[1][0], 0, 0, 0);
      acc1[1][1] = __builtin_amdgcn_mfma_f32_16x16x32_fp8_fp8((long)a1.y, (long)b1.y, acc1[1][1], 0, 0, 0);

      if (ks == NKS - 1) {
        // ---- relu + quantize -> H (swizzled row-major byte writes) ----
#pragma unroll
        for (int mi = 0; mi < 2; ++mi)
#pragma unroll
          for (int ni = 0; ni < 2; ++ni) {
            f32x4 v = acc1[mi][ni];
            int dh = wn * 32 + ni * 16 + lr;
            int rb = wm * 32 + mi * 16 + 4 * lg;
            int p01 = __builtin_amdgcn_cvt_pk_fp8_f32(fmaxf(v[0], 0.f),
                                                      fmaxf(v[1], 0.f), 0, false);
            int p23 = __builtin_amdgcn_cvt_pk_fp8_f32(fmaxf(v[2], 0.f),
                                                      fmaxf(v[3], 0.f), 0, false);
            H[(rb + 0) * 128 + (dh ^ (((rb + 0) & 7) << 4))] = (unsigned char)(p01 & 0xff);
            H[(rb + 1) * 128 + (dh ^ (((rb + 1) & 7) << 4))] = (unsigned char)((p01 >> 8) & 0xff);
            H[(rb + 2) * 128 + (dh ^ (((rb + 2) & 7) << 4))] = (unsigned char)(p23 & 0xff);
            H[(rb + 3) * 128 + (dh ^ (((rb + 3) & 7) << 4))] = (unsigned char)((p23 >> 8) & 0xff);
          }
        asm volatile("s_waitcnt lgkmcnt(0)" ::: "memory");
        __builtin_amdgcn_s_barrier();
        asm volatile("" ::: "memory");
        // ---- fc2: 2 MFMAs per wave on this chunk's dh-half ----
#pragma unroll
        for (int kk = 0; kk < 2; ++kk) {
          int dhl = wk * 64 + kk * 32 + lg * 8;
          long b2 = *(const long long*)(w2q + (size_t)lr * DH + nch * 128 + dhl);
          int hr = wh * 16 + lr;
          long a2 = *(const long long*)&H[hr * 128 + (dhl ^ ((hr & 7) << 4))];
          acc2 = __builtin_amdgcn_mfma_f32_16x16x32_fp8_fp8(a2, b2, acc2, 0, 0, 0);
        }
      }

      // next tile landed; one barrier per K-step
      asm volatile("s_waitcnt vmcnt(0)" ::: "memory");
      __builtin_amdgcn_s_barrier();
      asm volatile("" ::: "memory");
      buf ^= 1;
    }
  }

  // ---- pair-reduce fc2 halves (waves w and w+4 share rows), store ----
  __syncthreads();
  float* red = (float*)&Bt[0][0];
  if (wk == 1) {
#pragma unroll
    for (int j = 0; j < 4; ++j)
      red[(wh * 16 + 4 * lg + j) * 16 + lr] = acc2[j];
  }
  __syncthreads();
  if (wk == 0 && lr < 10) {
#pragma unroll
    for (int j = 0; j < 4; ++j) {
      int rloc = wh * 16 + 4 * lg + j;
      out[(row0 + rloc) * 10 + lr] = acc2[j] + red[rloc * 16 + lr];
    }
  }
#undef STAGE
}

extern "C" void kernel_launch(void* const* d_in, const int* in_sizes, int n_in,
                              void* d_out, int out_size, void* d_ws, size_t ws_size,
                              hipStream_t stream) {
  const float* x  = (const float*)d_in[0];
  const float* w1 = (const float*)d_in[1];
  const float* w2 = (const float*)d_in[2];
  float* out = (float*)d_out;

  unsigned char* w1q = (unsigned char*)d_ws;            // [4096][832] fp8 (interleaved)
  unsigned char* w2q = w1q + (size_t)DH * KP;           // [16][4096] fp8

  quant_w1_k<<<(DH * 52) / 256, 256, 0, stream>>>(w1, w1q);
  quant_w2_k<<<16, 256, 0, stream>>>(w2, w2q);
  fused_mlp<<<32768 / 64, 512, 0, stream>>>(x, w1q, w2q, out);
}

// Round 3
// 228.307 us; speedup vs baseline: 1.6248x; 1.0175x over previous
//
#include <hip/hip_runtime.h>

// FP8 MLP, fully fused:  out = q(relu(q(x)@q(w1)^T)) @ q(w2)^T
// x[32768,784] f32, w1[4096,784] f32, w2[10,4096] f32, out[32768,10] f32.
// R3: slot-XOR swizzle on A/Bt frag reads (2-way bank floor); fc1 computes
// mfma(w1, x) so the output register axis runs along dh -> H epilogue is
// 4x ds_write_b32 per thread instead of 16x ds_write_b8; w2 loads hoisted.

typedef float f32x4 __attribute__((ext_vector_type(4)));

#define DIN 784
#define KP  832          // 13 * 64 (zero-padded K)
#define DH  4096
#define NKS 13
#define NCH 32

__device__ __forceinline__ void gload_lds16(const void* g, void* l) {
  __builtin_amdgcn_global_load_lds(
      (const __attribute__((address_space(1))) unsigned int*)g,
      (__attribute__((address_space(3))) unsigned int*)l, 16, 0, 0);
}

__device__ __forceinline__ unsigned long long q8(float4 a, float4 b) {
  int lo = __builtin_amdgcn_cvt_pk_fp8_f32(a.x, a.y, 0, false);
  lo     = __builtin_amdgcn_cvt_pk_fp8_f32(a.z, a.w, lo, true);
  int hi = __builtin_amdgcn_cvt_pk_fp8_f32(b.x, b.y, 0, false);
  hi     = __builtin_amdgcn_cvt_pk_fp8_f32(b.z, b.w, hi, true);
  return (unsigned long long)(unsigned)lo |
         ((unsigned long long)(unsigned)hi << 32);
}

// ---------- weight quantization (fp32 -> OCP e4m3, RNE via HW cvt) ----------
// w1q row n = 13 k-blocks of 64B; block ks = 4 groups g of 16B;
// group g = { q(w1[n][ks*64+g*8 .. +8]) , q(w1[n][ks*64+32+g*8 .. +8]) }.

__global__ __launch_bounds__(256) void quant_w1_k(const float* __restrict__ w1,
                                                  unsigned char* __restrict__ w1q) {
  int idx = blockIdx.x * 256 + threadIdx.x;       // 4096 n * 52 groups
  int n = idx / 52, g = idx % 52;
  int ks = g >> 2, lg = g & 3;
  int kA = ks * 64 + lg * 8, kB = kA + 32;
  const float* r = w1 + (size_t)n * DIN;
  unsigned long long va = 0ull, vb = 0ull;
  if (kA < DIN) va = q8(*(const float4*)(r + kA), *(const float4*)(r + kA + 4));
  if (kB < DIN) vb = q8(*(const float4*)(r + kB), *(const float4*)(r + kB + 4));
  ulonglong2 v; v.x = va; v.y = vb;
  *(ulonglong2*)(w1q + (size_t)n * KP + ks * 64 + lg * 16) = v;
}

__global__ __launch_bounds__(256) void quant_w2_k(const float* __restrict__ w2,
                                                  unsigned char* __restrict__ w2q) {
  int idx = blockIdx.x * 256 + threadIdx.x;       // 16 rows * 256 chunks(16B)
  int r = idx >> 8, c = idx & 255;
  ulonglong2 v; v.x = 0ull; v.y = 0ull;
  if (r < 10) {
    const float* p = w2 + (size_t)r * DH + c * 16;
    v.x = q8(*(const float4*)(p), *(const float4*)(p + 4));
    v.y = q8(*(const float4*)(p + 8), *(const float4*)(p + 12));
  }
  *(ulonglong2*)(w2q + (size_t)r * DH + c * 16) = v;  // rows 10..15 = 0
}

// ------------------------------ fused MLP -----------------------------------
// Block = 512 threads (8 waves), owns 64 batch rows. Grid = 512 -> 2 blk/CU.
// LDS: A panel 52KB ([ks13][r64][slot4][16B], slot = g ^ ((r>>1)&3)),
//      Bt dbuf 2x8KB (same slot swizzle), H 8KB ([r64][dh128], byte-swizzled).
// fc1: mfma(A=w1, B=x): waves (w&3)->dh quad, (w>>2)->batch half; 32x32/wave.
// fc2: wave w -> rows (w&3)*16, dh-half (w>>2)*64; pair-reduced at the end.

__global__ __launch_bounds__(512, 4)
void fused_mlp(const float* __restrict__ x,
               const unsigned char* __restrict__ w1q,
               const unsigned char* __restrict__ w2q,
               float* __restrict__ out) {
  __shared__ unsigned char A[NKS * 4096];   // 52 KB
  __shared__ unsigned char Bt[2][8192];     // 16 KB
  __shared__ unsigned char H[8192];         // 8 KB

  const int tid = threadIdx.x;
  const int lane = tid & 63;
  const int w  = tid >> 6;
  const int lr = lane & 15;
  const int lg = lane >> 4;
  const int sl = lg ^ ((lr >> 1) & 3);      // storage slot of logical group lg
  const int wdh = (w & 3) * 32;             // fc1: dh offset of this wave
  const int wb  = (w >> 2) * 32;            // fc1: batch offset
  const int wh = w & 3, wk = w >> 2;        // fc2: row quad / dh half
  const long row0 = (long)blockIdx.x * 64;

#define STAGE(nch_, ks_, b_)                                                   \
  do {                                                                         \
    int n_ = tid >> 2, s_ = tid & 3, g_ = s_ ^ ((n_ >> 1) & 3);                \
    gload_lds16(w1q + (size_t)((nch_)*128 + n_) * KP + (ks_)*64 + g_*16,       \
                &Bt[b_][tid * 16]);                                            \
  } while (0)

  STAGE(0, 0, 0);   // in flight under the prologue

  // ---- prologue: quantize this block's 64 x-rows into the A panel ----
  for (int idx = tid; idx < NKS * 256; idx += 512) {
    int ks = idx >> 8, rem = idx & 255, r = rem >> 2, lgq = rem & 3;
    int kA = ks * 64 + lgq * 8, kB = kA + 32;
    const float* xr = x + (row0 + r) * DIN;
    unsigned long long va = 0ull, vb = 0ull;
    if (kA < DIN) va = q8(*(const float4*)(xr + kA), *(const float4*)(xr + kA + 4));
    if (kB < DIN) vb = q8(*(const float4*)(xr + kB), *(const float4*)(xr + kB + 4));
    ulonglong2 v; v.x = va; v.y = vb;
    int s_ = lgq ^ ((r >> 1) & 3);
    *(ulonglong2*)&A[ks * 4096 + r * 64 + s_ * 16] = v;
  }
  __syncthreads();   // A panel ready; first B tile drained

  // loop-invariant LDS byte offsets
  const int xoff0 = (wb + lr) * 64 + sl * 16;        // x frag ni=0
  const int xoff1 = xoff0 + 16 * 64;                 // x frag ni=1
  const int woff0 = (wdh + lr) * 64 + sl * 16;       // w1 frag mi=0
  const int woff1 = woff0 + 16 * 64;                 // w1 frag mi=1
  const int hr = wh * 16 + lr;                       // fc2 batch row
  const int hswz = (hr & 7) << 4;

  f32x4 acc2 = {};
  int buf = 0;
  for (int nch = 0; nch < NCH; ++nch) {
    // hoist fc2 weight loads for this chunk (consumed at ks == NKS-1)
    const unsigned char* w2p = w2q + (size_t)lr * DH + nch * 128 + wk * 64 + lg * 8;
    long b2a = *(const long long*)(w2p);
    long b2b = *(const long long*)(w2p + 32);

    f32x4 acc1[2][2] = {{{}, {}}, {{}, {}}};
#pragma unroll
    for (int ks = 0; ks < NKS; ++ks) {
      if (ks < NKS - 1)       STAGE(nch, ks + 1, buf ^ 1);
      else if (nch < NCH - 1) STAGE(nch + 1, 0, buf ^ 1);

      // ---- fc1: 4 swizzled b128 frag reads, 8 MFMAs (A=w1, B=x) ----
      ulonglong2 w0 = *(const ulonglong2*)&Bt[buf][woff0];
      ulonglong2 w1f = *(const ulonglong2*)&Bt[buf][woff1];
      ulonglong2 x0 = *(const ulonglong2*)&A[ks * 4096 + xoff0];
      ulonglong2 x1 = *(const ulonglong2*)&A[ks * 4096 + xoff1];
      acc1[0][0] = __builtin_amdgcn_mfma_f32_16x16x32_fp8_fp8((long)w0.x,  (long)x0.x, acc1[0][0], 0, 0, 0);
      acc1[0][1] = __builtin_amdgcn_mfma_f32_16x16x32_fp8_fp8((long)w0.x,  (long)x1.x, acc1[0][1], 0, 0, 0);
      acc1[1][0] = __builtin_amdgcn_mfma_f32_16x16x32_fp8_fp8((long)w1f.x, (long)x0.x, acc1[1][0], 0, 0, 0);
      acc1[1][1] = __builtin_amdgcn_mfma_f32_16x16x32_fp8_fp8((long)w1f.x, (long)x1.x, acc1[1][1], 0, 0, 0);
      acc1[0][0] = __builtin_amdgcn_mfma_f32_16x16x32_fp8_fp8((long)w0.y,  (long)x0.y, acc1[0][0], 0, 0, 0);
      acc1[0][1] = __builtin_amdgcn_mfma_f32_16x16x32_fp8_fp8((long)w0.y,  (long)x1.y, acc1[0][1], 0, 0, 0);
      acc1[1][0] = __builtin_amdgcn_mfma_f32_16x16x32_fp8_fp8((long)w1f.y, (long)x0.y, acc1[1][0], 0, 0, 0);
      acc1[1][1] = __builtin_amdgcn_mfma_f32_16x16x32_fp8_fp8((long)w1f.y, (long)x1.y, acc1[1][1], 0, 0, 0);

      if (ks == NKS - 1) {
        // ---- relu + quantize -> H: one b32 per (mi,ni), 4 dh bytes ----
#pragma unroll
        for (int mi = 0; mi < 2; ++mi)
#pragma unroll
          for (int ni = 0; ni < 2; ++ni) {
            f32x4 v = acc1[mi][ni];
            int rB  = wb + ni * 16 + lr;            // batch row (D col = lr)
            int dhc = wdh + mi * 16 + lg * 4;       // dh col base (D rows)
            unsigned int wv = (unsigned)__builtin_amdgcn_cvt_pk_fp8_f32(
                fmaxf(v[0], 0.f), fmaxf(v[1], 0.f), 0, false);
            wv = (unsigned)__builtin_amdgcn_cvt_pk_fp8_f32(
                fmaxf(v[2], 0.f), fmaxf(v[3], 0.f), (int)wv, true);
            *(unsigned int*)&H[rB * 128 + (dhc ^ ((rB & 7) << 4))] = wv;
          }
        asm volatile("s_waitcnt lgkmcnt(0)" ::: "memory");
        __builtin_amdgcn_s_barrier();
        asm volatile("" ::: "memory");
        // ---- fc2: 2 MFMAs per wave on this chunk's dh-half ----
        {
          int dhl0 = wk * 64 + lg * 8;
          long a20 = *(const long long*)&H[hr * 128 + (dhl0 ^ hswz)];
          long a21 = *(const long long*)&H[hr * 128 + ((dhl0 + 32) ^ hswz)];
          acc2 = __builtin_amdgcn_mfma_f32_16x16x32_fp8_fp8(a20, b2a, acc2, 0, 0, 0);
          acc2 = __builtin_amdgcn_mfma_f32_16x16x32_fp8_fp8(a21, b2b, acc2, 0, 0, 0);
        }
      }

      // next tile landed; one barrier per K-step
      asm volatile("s_waitcnt vmcnt(0)" ::: "memory");
      __builtin_amdgcn_s_barrier();
      asm volatile("" ::: "memory");
      buf ^= 1;
    }
  }

  // ---- pair-reduce fc2 halves (waves w and w+4 share rows), store ----
  __syncthreads();
  float* red = (float*)&Bt[0][0];
  if (wk == 1) {
#pragma unroll
    for (int j = 0; j < 4; ++j)
      red[(wh * 16 + 4 * lg + j) * 16 + lr] = acc2[j];
  }
  __syncthreads();
  if (wk == 0 && lr < 10) {
#pragma unroll
    for (int j = 0; j < 4; ++j) {
      int rloc = wh * 16 + 4 * lg + j;
      out[(row0 + rloc) * 10 + lr] = acc2[j] + red[rloc * 16 + lr];
    }
  }
#undef STAGE
}

extern "C" void kernel_launch(void* const* d_in, const int* in_sizes, int n_in,
                              void* d_out, int out_size, void* d_ws, size_t ws_size,
                              hipStream_t stream) {
  const float* x  = (const float*)d_in[0];
  const float* w1 = (const float*)d_in[1];
  const float* w2 = (const float*)d_in[2];
  float* out = (float*)d_out;

  unsigned char* w1q = (unsigned char*)d_ws;            // [4096][832] fp8 (interleaved)
  unsigned char* w2q = w1q + (size_t)DH * KP;           // [16][4096] fp8

  quant_w1_k<<<(DH * 52) / 256, 256, 0, stream>>>(w1, w1q);
  quant_w2_k<<<16, 256, 0, stream>>>(w2, w2q);
  fused_mlp<<<32768 / 64, 512, 0, stream>>>(x, w1q, w2q, out);
}